// Round 6
// baseline (243.364 us; speedup 1.0000x reference)
//
#include <hip/hip_runtime.h>
#include <stdint.h>

// ---------------- constants ----------------
#define DIM   768
#define NTOK  196
#define TT    8
#define MROWS 25088      // 3136 * 8
#define HEADS 12
#define NKT   12         // 768 / 64 K-tiles

typedef __bf16 bf16x8 __attribute__((ext_vector_type(8)));
typedef float  f32x4  __attribute__((ext_vector_type(4)));
typedef float  f32x16 __attribute__((ext_vector_type(16)));
typedef unsigned short u16x4 __attribute__((ext_vector_type(4)));
typedef unsigned short u16x8 __attribute__((ext_vector_type(8)));

typedef __attribute__((address_space(1))) const void GAS;
typedef __attribute__((address_space(3))) void LAS;

__device__ inline unsigned short f2bf(float f) {
  uint32_t u = __builtin_bit_cast(uint32_t, f);
  u += 0x7FFFu + ((u >> 16) & 1u);          // RNE
  return (unsigned short)(u >> 16);
}
__device__ inline float bf2f(unsigned short s) {
  uint32_t u = ((uint32_t)s) << 16;
  return __builtin_bit_cast(float, u);
}
__device__ inline void gl_lds16(const unsigned short* g, unsigned short* l) {
  __builtin_amdgcn_global_load_lds((GAS*)g, (LAS*)l, 16, 0, 0);
}
__device__ inline int xcd_swz(int orig, int nwg) {   // bijective (m204)
  int xcd = orig & 7, loc = orig >> 3;
  int q = nwg >> 3, r = nwg & 7;
  int base = (xcd < r) ? xcd * (q + 1) : r * (q + 1) + (xcd - r) * q;
  return base + loc;
}

#define WAITV(n) asm volatile("s_waitcnt vmcnt(" #n ")" ::: "memory")
#define CFENCE   asm volatile("" ::: "memory")
#define TBAR     do { CFENCE; __builtin_amdgcn_s_barrier(); CFENCE; } while (0)

// ---------------- weight fp32 -> bf16 convert ----------------
__global__ void wprep_kernel(const float* __restrict__ wq,
                             const float* __restrict__ wkv,
                             const float* __restrict__ wproj,
                             unsigned short* __restrict__ out) {
  int idx4 = blockIdx.x * blockDim.x + threadIdx.x;
  const int total4 = 2359296 / 4;
  if (idx4 >= total4) return;
  int e = idx4 * 4;
  const float* src; int off;
  if (e < 589824)        { src = wq;    off = e; }
  else if (e < 1769472)  { src = wkv;   off = e - 589824; }
  else                   { src = wproj; off = e - 1769472; }
  f32x4 v = *reinterpret_cast<const f32x4*>(&src[off]);
  u16x4 o;
  o[0] = f2bf(v[0]); o[1] = f2bf(v[1]); o[2] = f2bf(v[2]); o[3] = f2bf(v[3]);
  *reinterpret_cast<u16x4*>(&out[e]) = o;
}

// ---------------- CLS row copy (exact fp32) ----------------
__global__ void cls_kernel(const float* __restrict__ sx, float* __restrict__ out) {
  int i4 = blockIdx.x * blockDim.x + threadIdx.x;
  if (i4 < (128 * 768) / 4)
    reinterpret_cast<f32x4*>(out)[i4] = reinterpret_cast<const f32x4*>(sx)[i4];
}

// ---------------- A prep: gather + time_pos + fp32->bf16 ----------------
template<int MODE>
__global__ __launch_bounds__(256)
void aprep_kernel(const float* __restrict__ src, const float* __restrict__ timepos,
                  unsigned short* __restrict__ dst) {
  int idx = blockIdx.x * blockDim.x + threadIdx.x;      // one per 8 elems
  const int total = MROWS * (DIM / 8);
  if (idx >= total) return;
  int m  = idx / 96;
  int c8 = (idx - m * 96) * 8;
  int bn = m >> 3, t = m & 7;
  int b  = bn / NTOK, n = bn - b * NTOK;
  int srow = (MODE == 0) ? ((1 + n) * 128 + b * 8 + t)
                         : (b * (TT * NTOK) + t * NTOK + n);
  const float* sp = &src[srow * DIM + c8];
  const float* pp = &timepos[t * DIM + c8];
  f32x4 a0 = reinterpret_cast<const f32x4*>(sp)[0];
  f32x4 a1 = reinterpret_cast<const f32x4*>(sp)[1];
  f32x4 p0 = reinterpret_cast<const f32x4*>(pp)[0];
  f32x4 p1 = reinterpret_cast<const f32x4*>(pp)[1];
  a0 += p0; a1 += p1;
  u16x8 o;
  o[0] = f2bf(a0[0]); o[1] = f2bf(a0[1]); o[2] = f2bf(a0[2]); o[3] = f2bf(a0[3]);
  o[4] = f2bf(a1[0]); o[5] = f2bf(a1[1]); o[6] = f2bf(a1[2]); o[7] = f2bf(a1[3]);
  *reinterpret_cast<u16x8*>(&dst[m * DIM + c8]) = o;
}

// =====================================================================
// 8-phase 256x256 GEMM — 32x32x16 MFMA + reg-cached B.
// 8 waves = 2M x 4N; per-wave C = 128x64 as 2mq x 2nq quadrants of 64x32;
// quadrant = 2 fm-tiles (32 rows) x 1 col-tile (32) x 4 k-steps of 16.
// LDS: 8 half-tile slots of [128][64] bf16 (16 KB): slot = buf*4 + op*2 + half
// Phase ledger (identical to round-5, verified):
//  p1 (b0,mq0,nq0,RA,RB): stage slot5<-A1,kt1    p5 (b1,0,0,RA,RB): slot1<-A1,kt2
//  p2 (b0,0,1,   RB   ): stage slot7<-B1,kt1    p6 (b1,0,1,RB): slot3<-B1,kt2
//  p3 (b0,1,0,RA      ): stage slot0<-A0,kt2    p7 (b1,1,0,RA): slot4<-A0,kt3
//  p4 (b0,1,1         ): stage slot2<-B0,kt2;W4 p8 (b1,1,1): slot6<-B0,kt3;W4
// B frags (bq_[nq][ks]) read at mq0-phases, reused at mq1 -> 48 ds_reads/iter.
// vmcnt(4) at p4/p8 leaves exactly the 2 newest half-tiles in flight.
// =====================================================================
#define PHASE(buf, mq, nq, RA, RB, STG)                                       \
  {                                                                           \
    const unsigned short* As_ = &SB[((buf) * 4 + (mq)) * 8192];               \
    const unsigned short* Bs_ = &SB[((buf) * 4 + 2 + (nq)) * 8192];           \
    if (RA) {                                                                 \
      _Pragma("unroll")                                                       \
      for (int ks = 0; ks < 4; ++ks)                                          \
        _Pragma("unroll")                                                     \
        for (int fm = 0; fm < 2; ++fm) {                                      \
          int r = wm * 64 + fm * 32 + (lane & 31);                            \
          int c = ks * 16 + (lane >> 5) * 8;                                  \
          af[ks][fm] = *reinterpret_cast<const bf16x8*>(                      \
              &As_[r * 64 + (c ^ ((r & 7) << 3))]);                           \
        }                                                                     \
    }                                                                         \
    if (RB) {                                                                 \
      _Pragma("unroll")                                                       \
      for (int ks = 0; ks < 4; ++ks) {                                        \
        int r = wn * 32 + (lane & 31);                                        \
        int c = ks * 16 + (lane >> 5) * 8;                                    \
        bq_[nq][ks] = *reinterpret_cast<const bf16x8*>(                       \
            &Bs_[r * 64 + (c ^ ((r & 7) << 3))]);                             \
      }                                                                       \
    }                                                                         \
    STG;                                                                      \
    TBAR;                                                                     \
    asm volatile("s_waitcnt lgkmcnt(0)" ::: "memory");                        \
    __builtin_amdgcn_sched_barrier(0);                                        \
    __builtin_amdgcn_s_setprio(1);                                            \
    _Pragma("unroll")                                                         \
    for (int ks = 0; ks < 4; ++ks)                                            \
      _Pragma("unroll")                                                       \
      for (int fm = 0; fm < 2; ++fm)                                          \
        acc[mq][nq][fm] = __builtin_amdgcn_mfma_f32_32x32x16_bf16(            \
            af[ks][fm], bq_[nq][ks], acc[mq][nq][fm], 0, 0, 0);               \
    __builtin_amdgcn_s_setprio(0);                                            \
  }

__global__ __launch_bounds__(512, 1)
void gemm8p(const unsigned short* __restrict__ As,
            const unsigned short* __restrict__ At,
            const unsigned short* __restrict__ Wqb,
            const unsigned short* __restrict__ Wkvb,
            const float* __restrict__ bq,
            const float* __restrict__ bkv,
            unsigned short* __restrict__ qo,
            unsigned short* __restrict__ kvo,
            int bid0) {
  __shared__ unsigned short SB[8 * 8192];   // 128 KB
  const int tid  = threadIdx.x;
  const int lane = tid & 63;
  const int w    = tid >> 6;                // 0..7
  const int wm   = w >> 2;                  // 0..1
  const int wn   = w & 3;                   // 0..3

  int bid = xcd_swz(blockIdx.x, gridDim.x) + bid0;
  const unsigned short *Ag, *Wg; const float* bias;
  unsigned short* ob; int rt, ct, Ncols; bool isq;
  if (bid < 294) { isq = true;  rt = bid / 3; ct = bid % 3; Ag = As; Wg = Wqb;  bias = bq;  ob = qo;  Ncols = 768; }
  else { isq = false; int b2 = bid - 294; rt = b2 / 6; ct = b2 % 6; Ag = At; Wg = Wkvb; bias = bkv; ob = kvo; Ncols = 1536; }
  const int m0 = rt * 256, n0 = ct * 256;

  // bias preload first (keeps stray vmem out of the loop ledger)
  float bsv[2];
  #pragma unroll
  for (int q = 0; q < 2; ++q)
    bsv[q] = bias[n0 + q * 128 + wn * 32 + (lane & 31)];

  // stage one half-tile (2 x global_load_lds / thread, pre-swizzled source)
  auto stage = [&](int slot, const unsigned short* src, int base_row, int kt) {
    unsigned short* dst = &SB[slot * 8192];
    #pragma unroll
    for (int rr = 0; rr < 2; ++rr) {
      int srow = rr * 64 + w * 8 + (lane >> 3);
      int scol = ((lane & 7) * 8) ^ ((srow & 7) << 3);
      gl_lds16(&src[(size_t)(base_row + srow) * DIM + kt * 64 + scol],
               dst + (rr * 512 + w * 64) * 8);
    }
  };

  f32x16 acc[2][2][2] = {};
  bf16x8 af[4][2];
  bf16x8 bq_[2][4];

  // prologue: tile0 complete + tile1 {A0,B0}  (12 loads/thread)
  stage(0, Ag, m0,       0);
  stage(1, Ag, m0 + 128, 0);
  stage(2, Wg, n0,       0);
  stage(3, Wg, n0 + 128, 0);
  stage(4, Ag, m0,       1);
  stage(6, Wg, n0,       1);
  WAITV(4);                      // tile0 landed (newest 4 = tile1 loads)
  TBAR;

  for (int i = 0; i < NKT / 2; ++i) {
    const int kt1 = 2 * i + 1, kt2 = 2 * i + 2, kt3 = 2 * i + 3;
    const bool g2 = kt2 < NKT, g3 = kt3 < NKT, last = (i == NKT / 2 - 1);

    PHASE(0, 0, 0, 1, 1, (stage(5, Ag, m0 + 128, kt1)));
    TBAR;
    PHASE(0, 0, 1, 0, 1, (stage(7, Wg, n0 + 128, kt1)));
    TBAR;
    PHASE(0, 1, 0, 1, 0, (g2 ? stage(0, Ag, m0, kt2) : void()));
    TBAR;
    PHASE(0, 1, 1, 0, 0, (g2 ? stage(2, Wg, n0, kt2) : void()));
    if (last) { WAITV(0); } else { WAITV(4); }   // tile kt1 fully landed
    TBAR;
    PHASE(1, 0, 0, 1, 1, (g2 ? stage(1, Ag, m0 + 128, kt2) : void()));
    TBAR;
    PHASE(1, 0, 1, 0, 1, (g2 ? stage(3, Wg, n0 + 128, kt2) : void()));
    TBAR;
    PHASE(1, 1, 0, 1, 0, (g3 ? stage(4, Ag, m0, kt3) : void()));
    TBAR;
    PHASE(1, 1, 1, 0, 0, (g3 ? stage(6, Wg, n0, kt3) : void()));
    if (!last) { WAITV(4); }                     // tile kt2 fully landed
    TBAR;
  }

  // ---- epilogue: C layout 32x32 = col(lane&31), row (reg&3)+8*(reg>>2)+4*(lane>>5)
  #pragma unroll
  for (int mq = 0; mq < 2; ++mq)
    #pragma unroll
    for (int nq = 0; nq < 2; ++nq)
      #pragma unroll
      for (int fm = 0; fm < 2; ++fm) {
        int col  = n0 + nq * 128 + wn * 32 + (lane & 31);
        int rowb = m0 + mq * 128 + wm * 64 + fm * 32 + 4 * (lane >> 5);
        #pragma unroll
        for (int reg = 0; reg < 16; ++reg) {
          int row = rowb + (reg & 3) + 8 * (reg >> 2);
          float v = acc[mq][nq][fm][reg] + bsv[nq];
          if (isq) v *= 0.125f;               // attention scale (pow2, exact)
          ob[(size_t)row * Ncols + col] = f2bf(v);
        }
      }
}

// ---------------- proj GEMM: ring-3 counted-vmcnt, 32x32x16 MFMA ------------
// BM=256, BN=128, BK=64, 8 waves (2m x 4n, per-wave 128x32);
// reads clustered (20 ds_read_b128) before the 16 MFMAs per K-tile.
__global__ __launch_bounds__(512)
void gemm_proj(const unsigned short* __restrict__ Ag,
               const unsigned short* __restrict__ Wg,
               const float* __restrict__ bias,
               float* __restrict__ fout) {
  __shared__ unsigned short SB[3 * 24576];

  const int tid  = threadIdx.x;
  const int lane = tid & 63;
  const int w    = tid >> 6;
  const int wm   = w >> 2, wn = w & 3;

  int bid = xcd_swz(blockIdx.x, gridDim.x);
  const int rt = bid / 6, ct = bid % 6;
  const int m0 = rt * 256, n0 = ct * 128;

  auto stageA = [&](int kt) {
    const int kb = kt * 64;
    unsigned short* dst = &SB[(kt % 3) * 24576];
    #pragma unroll
    for (int rnd = 0; rnd < 4; ++rnd) {
      int s    = rnd * 8 + w;
      int srow = s * 8 + (lane >> 3);
      int scol = ((lane & 7) * 8) ^ ((srow & 7) << 3);
      gl_lds16(&Ag[(size_t)(m0 + srow) * 768 + kb + scol], dst + s * 512);
    }
  };
  auto stageB = [&](int kt) {
    const int kb = kt * 64;
    unsigned short* dst = &SB[(kt % 3) * 24576 + 16384];
    #pragma unroll
    for (int rnd = 0; rnd < 2; ++rnd) {
      int s    = rnd * 8 + w;
      int srow = s * 8 + (lane >> 3);
      int scol = ((lane & 7) * 8) ^ ((srow & 7) << 3);
      gl_lds16(&Wg[(size_t)(n0 + srow) * 768 + kb + scol], dst + s * 512);
    }
  };

  f32x16 acc[4] = {};

  stageA(0); stageB(0);
  stageA(1); stageB(1);

  for (int kt = 0; kt < NKT; ++kt) {
    __builtin_amdgcn_sched_barrier(0);
    if (kt < NKT - 1) { WAITV(6); } else { WAITV(0); }
    __builtin_amdgcn_s_barrier();
    CFENCE;

    const unsigned short* Ab = &SB[(kt % 3) * 24576];
    const unsigned short* Bb = Ab + 16384;
    const bool st = (kt + 2) < NKT;

    if (st) stageA(kt + 2);
    __builtin_amdgcn_sched_barrier(0);

    // cluster all reads: 16 A-frags + 4 B-frags, then 16 MFMAs
    bf16x8 af[4][4], bfv[4];
    #pragma unroll
    for (int ks = 0; ks < 4; ++ks) {
      const int kc = ks * 16 + (lane >> 5) * 8;
      #pragma unroll
      for (int fm = 0; fm < 4; ++fm) {
        int r = wm * 128 + fm * 32 + (lane & 31);
        af[ks][fm] = *reinterpret_cast<const bf16x8*>(&Ab[r * 64 + (kc ^ ((r & 7) << 3))]);
      }
      int rb = wn * 32 + (lane & 31);
      bfv[ks] = *reinterpret_cast<const bf16x8*>(&Bb[rb * 64 + (kc ^ ((rb & 7) << 3))]);
    }
    if (st) stageB(kt + 2);
    __builtin_amdgcn_s_setprio(1);
    #pragma unroll
    for (int ks = 0; ks < 4; ++ks)
      #pragma unroll
      for (int fm = 0; fm < 4; ++fm)
        acc[fm] = __builtin_amdgcn_mfma_f32_32x32x16_bf16(af[ks][fm], bfv[ks], acc[fm], 0, 0, 0);
    __builtin_amdgcn_s_setprio(0);
    __builtin_amdgcn_sched_barrier(0);
  }

  // epilogue: per-thread col fixed, rows from 32x32 C layout
  const int col  = n0 + wn * 32 + (lane & 31);
  const float bsv = bias[col];
  #pragma unroll
  for (int fm = 0; fm < 4; ++fm) {
    const int rowb = m0 + wm * 128 + fm * 32 + 4 * (lane >> 5);
    #pragma unroll
    for (int reg = 0; reg < 16; ++reg) {
      int row = rowb + (reg & 3) + 8 * (reg >> 2);
      float v = acc[fm][reg] + bsv;
      int bn = row >> 3, t = row & 7;
      int b  = bn / NTOK, n = bn - b * NTOK;
      fout[((1 + n) * 128 + b * 8 + t) * DIM + col] = v;
    }
  }
}

// ---------------- attention: per (bn,h), t=8, hd=64 ----------------
__global__ __launch_bounds__(256)
void attn_kernel(const unsigned short* __restrict__ qb,
                 const unsigned short* __restrict__ kvb,
                 unsigned short* __restrict__ ob) {
  __shared__ __align__(16) float lds[4][3][8][68];
  const int tid  = threadIdx.x;
  const int lane = tid & 63;
  const int w    = tid >> 6;
  const int wid  = blockIdx.x * 4 + w;
  const int bn   = wid / HEADS;
  const int h    = wid - bn * HEADS;

  const int t  = lane >> 3;
  const int d0 = (lane & 7) * 8;
  const int qoff = (bn * 8 + t) * DIM + h * 64 + d0;
  const int koff = (bn * 8 + t) * (2 * DIM) + h * 64 + d0;

  u16x8 q8 = *reinterpret_cast<const u16x8*>(&qb[qoff]);
  u16x8 k8 = *reinterpret_cast<const u16x8*>(&kvb[koff]);
  u16x8 v8 = *reinterpret_cast<const u16x8*>(&kvb[koff + DIM]);
  f32x4 qa, qc, ka, kc, va, vc;
  #pragma unroll
  for (int e = 0; e < 4; ++e) {
    qa[e] = bf2f(q8[e]); qc[e] = bf2f(q8[e + 4]);
    ka[e] = bf2f(k8[e]); kc[e] = bf2f(k8[e + 4]);
    va[e] = bf2f(v8[e]); vc[e] = bf2f(v8[e + 4]);
  }
  *reinterpret_cast<f32x4*>(&lds[w][0][t][d0])     = qa;
  *reinterpret_cast<f32x4*>(&lds[w][0][t][d0 + 4]) = qc;
  *reinterpret_cast<f32x4*>(&lds[w][1][t][d0])     = ka;
  *reinterpret_cast<f32x4*>(&lds[w][1][t][d0 + 4]) = kc;
  *reinterpret_cast<f32x4*>(&lds[w][2][t][d0])     = va;
  *reinterpret_cast<f32x4*>(&lds[w][2][t][d0 + 4]) = vc;
  __syncthreads();

  const int i = lane >> 3, j = lane & 7;
  const f32x4* qi = reinterpret_cast<const f32x4*>(&lds[w][0][i][0]);
  const f32x4* kj = reinterpret_cast<const f32x4*>(&lds[w][1][j][0]);
  float s = 0.f;
  #pragma unroll
  for (int c = 0; c < 16; ++c) {
    f32x4 a = qi[c], b = kj[c];
    s += a[0] * b[0] + a[1] * b[1] + a[2] * b[2] + a[3] * b[3];
  }
  float m = s;
  m = fmaxf(m, __shfl_xor(m, 1));
  m = fmaxf(m, __shfl_xor(m, 2));
  m = fmaxf(m, __shfl_xor(m, 4));
  float e = __expf(s - m);
  float sum = e;
  sum += __shfl_xor(sum, 1);
  sum += __shfl_xor(sum, 2);
  sum += __shfl_xor(sum, 4);
  float p = e / sum;

  float o[8] = {};
  #pragma unroll
  for (int jj = 0; jj < 8; ++jj) {
    float pj = __shfl(p, (lane & 56) | jj);
    const f32x4* vj = reinterpret_cast<const f32x4*>(&lds[w][2][jj][d0]);
    f32x4 v0 = vj[0], v1 = vj[1];
    o[0] += pj * v0[0]; o[1] += pj * v0[1]; o[2] += pj * v0[2]; o[3] += pj * v0[3];
    o[4] += pj * v1[0]; o[5] += pj * v1[1]; o[6] += pj * v1[2]; o[7] += pj * v1[3];
  }
  u16x8 os;
  #pragma unroll
  for (int e2 = 0; e2 < 8; ++e2) os[e2] = f2bf(o[e2]);
  *reinterpret_cast<u16x8*>(&ob[qoff]) = os;
}

// ---------------- launch ----------------
extern "C" void kernel_launch(void* const* d_in, const int* in_sizes, int n_in,
                              void* d_out, int out_size, void* d_ws, size_t ws_size,
                              hipStream_t stream) {
  const float* s_x       = (const float*)d_in[0];
  const float* t_x       = (const float*)d_in[1];
  const float* clip_pos  = (const float*)d_in[2];
  const float* vmae_pos  = (const float*)d_in[3];
  const float* Wq        = (const float*)d_in[4];
  const float* q_bias    = (const float*)d_in[5];
  const float* Wkv       = (const float*)d_in[6];
  const float* kv_bias   = (const float*)d_in[7];
  const float* Wproj     = (const float*)d_in[8];
  const float* proj_bias = (const float*)d_in[9];
  float* out = (float*)d_out;

  char* ws = (char*)d_ws;
  unsigned short* w_bf = (unsigned short*)ws;                    // 4,718,592 B
  const size_t ABUF = 38535168, KVB = 77070336, WB = 4718592;
  const bool merged = ws_size >= (WB + 3 * ABUF + KVB);

  const unsigned short* wq_bf  = w_bf;
  const unsigned short* wkv_bf = w_bf + 589824;
  const unsigned short* wpj_bf = w_bf + 1769472;

  const int prep_blocks = (MROWS * 96 + 255) / 256;   // 9408

  wprep_kernel<<<dim3((589824 + 255) / 256), dim3(256), 0, stream>>>(Wq, Wkv, Wproj, w_bf);
  cls_kernel<<<dim3(96), dim3(256), 0, stream>>>(s_x, out);

  if (merged) {
    unsigned short* As    = (unsigned short*)(ws + WB);
    unsigned short* At    = (unsigned short*)(ws + WB + ABUF);
    unsigned short* q_bf  = (unsigned short*)(ws + WB + 2 * ABUF);
    unsigned short* kv_bf = (unsigned short*)(ws + WB + 3 * ABUF);
    aprep_kernel<0><<<dim3(prep_blocks), dim3(256), 0, stream>>>(s_x, clip_pos, As);
    aprep_kernel<1><<<dim3(prep_blocks), dim3(256), 0, stream>>>(t_x, vmae_pos, At);
    gemm8p<<<dim3(882), dim3(512), 0, stream>>>(As, At, wq_bf, wkv_bf, q_bias, kv_bias,
                                                q_bf, kv_bf, 0);
    attn_kernel<<<dim3(9408), dim3(256), 0, stream>>>(q_bf, kv_bf, As);
    gemm_proj<<<dim3(588), dim3(512), 0, stream>>>(As, wpj_bf, proj_bias, out);
  } else {
    unsigned short* buf1  = (unsigned short*)(ws + WB);
    unsigned short* q_bf  = (unsigned short*)(ws + WB + ABUF);
    unsigned short* kv_bf = (unsigned short*)(ws + WB + 2 * ABUF);
    aprep_kernel<0><<<dim3(prep_blocks), dim3(256), 0, stream>>>(s_x, clip_pos, buf1);
    gemm8p<<<dim3(294), dim3(512), 0, stream>>>(buf1, buf1, wq_bf, wkv_bf, q_bias, kv_bias,
                                                q_bf, kv_bf, 0);
    aprep_kernel<1><<<dim3(prep_blocks), dim3(256), 0, stream>>>(t_x, vmae_pos, buf1);
    gemm8p<<<dim3(588), dim3(512), 0, stream>>>(buf1, buf1, wq_bf, wkv_bf, q_bias, kv_bias,
                                                q_bf, kv_bf, 294);
    attn_kernel<<<dim3(9408), dim3(256), 0, stream>>>(q_bf, kv_bf, buf1);
    gemm_proj<<<dim3(588), dim3(512), 0, stream>>>(buf1, wpj_bf, proj_bias, out);
  }
}

// Round 7
// 210.544 us; speedup vs baseline: 1.1559x; 1.1559x over previous
//
#include <hip/hip_runtime.h>
#include <stdint.h>

// ---------------- constants ----------------
#define DIM   768
#define NTOK  196
#define TT    8
#define MROWS 25088      // 3136 * 8
#define HEADS 12
#define NKT   12         // 768 / 64 K-tiles

typedef __bf16 bf16x8 __attribute__((ext_vector_type(8)));
typedef float  f32x4  __attribute__((ext_vector_type(4)));
typedef unsigned short u16x4 __attribute__((ext_vector_type(4)));
typedef unsigned short u16x8 __attribute__((ext_vector_type(8)));

typedef __attribute__((address_space(1))) const void GAS;
typedef __attribute__((address_space(3))) void LAS;

__device__ inline unsigned short f2bf(float f) {
  uint32_t u = __builtin_bit_cast(uint32_t, f);
  u += 0x7FFFu + ((u >> 16) & 1u);          // RNE
  return (unsigned short)(u >> 16);
}
__device__ inline float bf2f(unsigned short s) {
  uint32_t u = ((uint32_t)s) << 16;
  return __builtin_bit_cast(float, u);
}
__device__ inline void gl_lds16(const unsigned short* g, unsigned short* l) {
  __builtin_amdgcn_global_load_lds((GAS*)g, (LAS*)l, 16, 0, 0);
}
__device__ inline int xcd_swz(int orig, int nwg) {   // bijective (m204)
  int xcd = orig & 7, loc = orig >> 3;
  int q = nwg >> 3, r = nwg & 7;
  int base = (xcd < r) ? xcd * (q + 1) : r * (q + 1) + (xcd - r) * q;
  return base + loc;
}

#define WAITV(n) asm volatile("s_waitcnt vmcnt(" #n ")" ::: "memory")
#define CFENCE   asm volatile("" ::: "memory")

// ---------------- weight fp32 -> bf16 convert ----------------
__global__ void wprep_kernel(const float* __restrict__ wq,
                             const float* __restrict__ wkv,
                             const float* __restrict__ wproj,
                             unsigned short* __restrict__ out) {
  int idx4 = blockIdx.x * blockDim.x + threadIdx.x;
  const int total4 = 2359296 / 4;
  if (idx4 >= total4) return;
  int e = idx4 * 4;
  const float* src; int off;
  if (e < 589824)        { src = wq;    off = e; }
  else if (e < 1769472)  { src = wkv;   off = e - 589824; }
  else                   { src = wproj; off = e - 1769472; }
  f32x4 v = *reinterpret_cast<const f32x4*>(&src[off]);
  u16x4 o;
  o[0] = f2bf(v[0]); o[1] = f2bf(v[1]); o[2] = f2bf(v[2]); o[3] = f2bf(v[3]);
  *reinterpret_cast<u16x4*>(&out[e]) = o;
}

// ---------------- CLS row copy (exact fp32) ----------------
__global__ void cls_kernel(const float* __restrict__ sx, float* __restrict__ out) {
  int i4 = blockIdx.x * blockDim.x + threadIdx.x;
  if (i4 < (128 * 768) / 4)
    reinterpret_cast<f32x4*>(out)[i4] = reinterpret_cast<const f32x4*>(sx)[i4];
}

// ---------------- A prep: gather + time_pos + fp32->bf16 -------------------
// ybase + blockIdx.y selects stream: 0 = s_x->dstS (clip), 1 = t_x->dstT (vmae)
__global__ __launch_bounds__(256)
void aprep2_kernel(const float* __restrict__ s_x, const float* __restrict__ t_x,
                   const float* __restrict__ clip, const float* __restrict__ vmae,
                   unsigned short* __restrict__ dstS, unsigned short* __restrict__ dstT,
                   int ybase) {
  int idx = blockIdx.x * blockDim.x + threadIdx.x;      // one per 8 elems
  const int total = MROWS * (DIM / 8);
  if (idx >= total) return;
  int m  = idx / 96;
  int c8 = (idx - m * 96) * 8;
  int bn = m >> 3, t = m & 7;
  int b  = bn / NTOK, n = bn - b * NTOK;
  const float* src; const float* tp; unsigned short* dst; int srow;
  if ((int)blockIdx.y + ybase == 0) {
    srow = (1 + n) * 128 + b * 8 + t; src = s_x; tp = clip; dst = dstS;
  } else {
    srow = b * (TT * NTOK) + t * NTOK + n; src = t_x; tp = vmae; dst = dstT;
  }
  const float* sp = &src[srow * DIM + c8];
  const float* pp = &tp[t * DIM + c8];
  f32x4 a0 = reinterpret_cast<const f32x4*>(sp)[0];
  f32x4 a1 = reinterpret_cast<const f32x4*>(sp)[1];
  f32x4 p0 = reinterpret_cast<const f32x4*>(pp)[0];
  f32x4 p1 = reinterpret_cast<const f32x4*>(pp)[1];
  a0 += p0; a1 += p1;
  u16x8 o;
  o[0] = f2bf(a0[0]); o[1] = f2bf(a0[1]); o[2] = f2bf(a0[2]); o[3] = f2bf(a0[3]);
  o[4] = f2bf(a1[0]); o[5] = f2bf(a1[1]); o[6] = f2bf(a1[2]); o[7] = f2bf(a1[3]);
  *reinterpret_cast<u16x8*>(&dst[m * DIM + c8]) = o;
}

// ---------------- QKV GEMM: ring-3 counted-vmcnt, 16x16 MFMA (round-4) -----
// BM=256, BN=128, BK=64, 8 waves (2m x 4n), per-wave 128x32; LDS 144 KB.
__global__ __launch_bounds__(512)
void gemm8(const unsigned short* __restrict__ As,
           const unsigned short* __restrict__ At,
           const unsigned short* __restrict__ W0,
           const unsigned short* __restrict__ W1,
           const float* __restrict__ b0,
           const float* __restrict__ b1,
           unsigned short* __restrict__ out0,
           unsigned short* __restrict__ out1,
           int bid0) {
  __shared__ unsigned short SB[3 * 24576];

  const int tid  = threadIdx.x;
  const int lane = tid & 63;
  const int w    = tid >> 6;
  const int wm   = w >> 2;
  const int wn   = w & 3;

  int bid = xcd_swz(blockIdx.x, gridDim.x) + bid0;

  const unsigned short *Ag, *Wg;
  const float* bias;
  unsigned short* ob;
  int rt, ct, Ncols;
  float scale = 1.0f;
  if (bid < 588) { rt = bid / 6;  ct = bid % 6;  Ag = As; Wg = W0; bias = b0; ob = out0; Ncols = 768;  scale = 0.125f; }
  else { int b2 = bid - 588; rt = b2 / 12; ct = b2 % 12; Ag = At; Wg = W1; bias = b1; ob = out1; Ncols = 1536; }
  const int m0 = rt * 256;
  const int n0 = ct * 128;

  auto stageA = [&](int kt) {
    const int kb = kt * 64;
    unsigned short* dst = &SB[(kt % 3) * 24576];
    #pragma unroll
    for (int rnd = 0; rnd < 4; ++rnd) {
      int s    = rnd * 8 + w;
      int srow = s * 8 + (lane >> 3);
      int scol = ((lane & 7) * 8) ^ ((srow & 7) << 3);
      gl_lds16(&Ag[(size_t)(m0 + srow) * 768 + kb + scol], dst + s * 512);
    }
  };
  auto stageB = [&](int kt) {
    const int kb = kt * 64;
    unsigned short* dst = &SB[(kt % 3) * 24576 + 16384];
    #pragma unroll
    for (int rnd = 0; rnd < 2; ++rnd) {
      int s    = rnd * 8 + w;
      int srow = s * 8 + (lane >> 3);
      int scol = ((lane & 7) * 8) ^ ((srow & 7) << 3);
      gl_lds16(&Wg[(size_t)(n0 + srow) * 768 + kb + scol], dst + s * 512);
    }
  };

  f32x4 acc[8][2] = {};

  stageA(0); stageB(0);
  stageA(1); stageB(1);

  for (int kt = 0; kt < NKT; ++kt) {
    __builtin_amdgcn_sched_barrier(0);
    if (kt < NKT - 1) { WAITV(6); } else { WAITV(0); }
    __builtin_amdgcn_s_barrier();
    CFENCE;

    const unsigned short* Ab = &SB[(kt % 3) * 24576];
    const unsigned short* Bb = Ab + 16384;
    const bool st = (kt + 2) < NKT;

    if (st) stageA(kt + 2);
    __builtin_amdgcn_sched_barrier(0);

    #pragma unroll
    for (int ks = 0; ks < 2; ++ks) {
      bf16x8 af[8], bfv[2];
      const int kc = ks * 32 + (lane >> 4) * 8;
      #pragma unroll
      for (int fm = 0; fm < 8; ++fm) {
        int r = wm * 128 + fm * 16 + (lane & 15);
        af[fm] = *reinterpret_cast<const bf16x8*>(&Ab[r * 64 + (kc ^ ((r & 7) << 3))]);
      }
      #pragma unroll
      for (int fn = 0; fn < 2; ++fn) {
        int r = wn * 32 + fn * 16 + (lane & 15);
        bfv[fn] = *reinterpret_cast<const bf16x8*>(&Bb[r * 64 + (kc ^ ((r & 7) << 3))]);
      }
      __builtin_amdgcn_s_setprio(1);
      #pragma unroll
      for (int fm = 0; fm < 8; ++fm)
        #pragma unroll
        for (int fn = 0; fn < 2; ++fn)
          acc[fm][fn] = __builtin_amdgcn_mfma_f32_16x16x32_bf16(af[fm], bfv[fn], acc[fm][fn], 0, 0, 0);
      __builtin_amdgcn_s_setprio(0);
      if (ks == 0 && st) stageB(kt + 2);
      __builtin_amdgcn_sched_barrier(0);
    }
  }

  #pragma unroll
  for (int fm = 0; fm < 8; ++fm) {
    #pragma unroll
    for (int fn = 0; fn < 2; ++fn) {
      int col = n0 + wn * 32 + fn * 16 + (lane & 15);
      float bsv = bias[col];
      #pragma unroll
      for (int i = 0; i < 4; ++i) {
        int row = m0 + wm * 128 + fm * 16 + (lane >> 4) * 4 + i;
        float v = (acc[fm][fn][i] + bsv) * scale;
        ob[(size_t)row * Ncols + col] = f2bf(v);
      }
    }
  }
}

// ---------------- proj GEMM: ring-3, BM=128 (1176 blocks, tail fix) --------
// BM=128, BN=128, BK=64, 8 waves (2m x 4n), per-wave 64x32; LDS 96 KB.
__global__ __launch_bounds__(512)
void gemm_proj(const unsigned short* __restrict__ Ag,
               const unsigned short* __restrict__ Wg,
               const float* __restrict__ bias,
               float* __restrict__ fout) {
  __shared__ unsigned short SB[3 * 16384];

  const int tid  = threadIdx.x;
  const int lane = tid & 63;
  const int w    = tid >> 6;
  const int wm   = w >> 2, wn = w & 3;

  int bid = xcd_swz(blockIdx.x, gridDim.x);
  const int rt = bid / 6, ct = bid % 6;
  const int m0 = rt * 128, n0 = ct * 128;

  auto stageP = [&](int kt, const unsigned short* src, int base_row, int half) {
    const int kb = kt * 64;
    unsigned short* dst = &SB[(kt % 3) * 16384 + half * 8192];
    #pragma unroll
    for (int rnd = 0; rnd < 2; ++rnd) {
      int s    = rnd * 8 + w;
      int srow = s * 8 + (lane >> 3);
      int scol = ((lane & 7) * 8) ^ ((srow & 7) << 3);
      gl_lds16(&src[(size_t)(base_row + srow) * 768 + kb + scol], dst + s * 512);
    }
  };

  f32x4 acc[4][2] = {};

  stageP(0, Ag, m0, 0); stageP(0, Wg, n0, 1);
  stageP(1, Ag, m0, 0); stageP(1, Wg, n0, 1);

  for (int kt = 0; kt < NKT; ++kt) {
    __builtin_amdgcn_sched_barrier(0);
    if (kt < NKT - 1) { WAITV(4); } else { WAITV(0); }
    __builtin_amdgcn_s_barrier();
    CFENCE;

    const unsigned short* Ab = &SB[(kt % 3) * 16384];
    const unsigned short* Bb = Ab + 8192;
    const bool st = (kt + 2) < NKT;

    if (st) stageP(kt + 2, Ag, m0, 0);
    __builtin_amdgcn_sched_barrier(0);

    #pragma unroll
    for (int ks = 0; ks < 2; ++ks) {
      bf16x8 af[4], bfv[2];
      const int kc = ks * 32 + (lane >> 4) * 8;
      #pragma unroll
      for (int fm = 0; fm < 4; ++fm) {
        int r = wm * 64 + fm * 16 + (lane & 15);
        af[fm] = *reinterpret_cast<const bf16x8*>(&Ab[r * 64 + (kc ^ ((r & 7) << 3))]);
      }
      #pragma unroll
      for (int fn = 0; fn < 2; ++fn) {
        int r = wn * 32 + fn * 16 + (lane & 15);
        bfv[fn] = *reinterpret_cast<const bf16x8*>(&Bb[r * 64 + (kc ^ ((r & 7) << 3))]);
      }
      __builtin_amdgcn_s_setprio(1);
      #pragma unroll
      for (int fm = 0; fm < 4; ++fm)
        #pragma unroll
        for (int fn = 0; fn < 2; ++fn)
          acc[fm][fn] = __builtin_amdgcn_mfma_f32_16x16x32_bf16(af[fm], bfv[fn], acc[fm][fn], 0, 0, 0);
      __builtin_amdgcn_s_setprio(0);
      if (ks == 0 && st) stageP(kt + 2, Wg, n0, 1);
      __builtin_amdgcn_sched_barrier(0);
    }
  }

  #pragma unroll
  for (int fm = 0; fm < 4; ++fm) {
    #pragma unroll
    for (int fn = 0; fn < 2; ++fn) {
      int col = n0 + wn * 32 + fn * 16 + (lane & 15);
      float bsv = bias[col];
      #pragma unroll
      for (int i = 0; i < 4; ++i) {
        int row = m0 + wm * 64 + fm * 16 + (lane >> 4) * 4 + i;
        float v = acc[fm][fn][i] + bsv;
        int bn = row >> 3, t = row & 7;
        int b  = bn / NTOK, n = bn - b * NTOK;
        fout[((1 + n) * 128 + b * 8 + t) * DIM + col] = v;
      }
    }
  }
}

// ---------------- attention: per (bn,h), t=8, hd=64 ----------------
__global__ __launch_bounds__(256)
void attn_kernel(const unsigned short* __restrict__ qb,
                 const unsigned short* __restrict__ kvb,
                 unsigned short* __restrict__ ob) {
  __shared__ __align__(16) float lds[4][3][8][68];
  const int tid  = threadIdx.x;
  const int lane = tid & 63;
  const int w    = tid >> 6;
  const int wid  = blockIdx.x * 4 + w;
  const int bn   = wid / HEADS;
  const int h    = wid - bn * HEADS;

  const int t  = lane >> 3;
  const int d0 = (lane & 7) * 8;
  const int qoff = (bn * 8 + t) * DIM + h * 64 + d0;
  const int koff = (bn * 8 + t) * (2 * DIM) + h * 64 + d0;

  u16x8 q8 = *reinterpret_cast<const u16x8*>(&qb[qoff]);
  u16x8 k8 = *reinterpret_cast<const u16x8*>(&kvb[koff]);
  u16x8 v8 = *reinterpret_cast<const u16x8*>(&kvb[koff + DIM]);
  f32x4 qa, qc, ka, kc, va, vc;
  #pragma unroll
  for (int e = 0; e < 4; ++e) {
    qa[e] = bf2f(q8[e]); qc[e] = bf2f(q8[e + 4]);
    ka[e] = bf2f(k8[e]); kc[e] = bf2f(k8[e + 4]);
    va[e] = bf2f(v8[e]); vc[e] = bf2f(v8[e + 4]);
  }
  *reinterpret_cast<f32x4*>(&lds[w][0][t][d0])     = qa;
  *reinterpret_cast<f32x4*>(&lds[w][0][t][d0 + 4]) = qc;
  *reinterpret_cast<f32x4*>(&lds[w][1][t][d0])     = ka;
  *reinterpret_cast<f32x4*>(&lds[w][1][t][d0 + 4]) = kc;
  *reinterpret_cast<f32x4*>(&lds[w][2][t][d0])     = va;
  *reinterpret_cast<f32x4*>(&lds[w][2][t][d0 + 4]) = vc;
  __syncthreads();

  const int i = lane >> 3, j = lane & 7;
  const f32x4* qi = reinterpret_cast<const f32x4*>(&lds[w][0][i][0]);
  const f32x4* kj = reinterpret_cast<const f32x4*>(&lds[w][1][j][0]);
  float s = 0.f;
  #pragma unroll
  for (int c = 0; c < 16; ++c) {
    f32x4 a = qi[c], b = kj[c];
    s += a[0] * b[0] + a[1] * b[1] + a[2] * b[2] + a[3] * b[3];
  }
  float m = s;
  m = fmaxf(m, __shfl_xor(m, 1));
  m = fmaxf(m, __shfl_xor(m, 2));
  m = fmaxf(m, __shfl_xor(m, 4));
  float e = __expf(s - m);
  float sum = e;
  sum += __shfl_xor(sum, 1);
  sum += __shfl_xor(sum, 2);
  sum += __shfl_xor(sum, 4);
  float p = e / sum;

  float o[8] = {};
  #pragma unroll
  for (int jj = 0; jj < 8; ++jj) {
    float pj = __shfl(p, (lane & 56) | jj);
    const f32x4* vj = reinterpret_cast<const f32x4*>(&lds[w][2][jj][d0]);
    f32x4 v0 = vj[0], v1 = vj[1];
    o[0] += pj * v0[0]; o[1] += pj * v0[1]; o[2] += pj * v0[2]; o[3] += pj * v0[3];
    o[4] += pj * v1[0]; o[5] += pj * v1[1]; o[6] += pj * v1[2]; o[7] += pj * v1[3];
  }
  u16x8 os;
  #pragma unroll
  for (int e2 = 0; e2 < 8; ++e2) os[e2] = f2bf(o[e2]);
  *reinterpret_cast<u16x8*>(&ob[qoff]) = os;
}

// ---------------- launch ----------------
extern "C" void kernel_launch(void* const* d_in, const int* in_sizes, int n_in,
                              void* d_out, int out_size, void* d_ws, size_t ws_size,
                              hipStream_t stream) {
  const float* s_x       = (const float*)d_in[0];
  const float* t_x       = (const float*)d_in[1];
  const float* clip_pos  = (const float*)d_in[2];
  const float* vmae_pos  = (const float*)d_in[3];
  const float* Wq        = (const float*)d_in[4];
  const float* q_bias    = (const float*)d_in[5];
  const float* Wkv       = (const float*)d_in[6];
  const float* kv_bias   = (const float*)d_in[7];
  const float* Wproj     = (const float*)d_in[8];
  const float* proj_bias = (const float*)d_in[9];
  float* out = (float*)d_out;

  char* ws = (char*)d_ws;
  unsigned short* w_bf = (unsigned short*)ws;                    // 4,718,592 B
  const size_t ABUF = 38535168, KVB = 77070336, WB = 4718592;
  const bool merged = ws_size >= (WB + 3 * ABUF + KVB);

  const unsigned short* wq_bf  = w_bf;
  const unsigned short* wkv_bf = w_bf + 589824;
  const unsigned short* wpj_bf = w_bf + 1769472;

  const int prep_blocks = (MROWS * 96 + 255) / 256;   // 9408

  wprep_kernel<<<dim3((589824 + 255) / 256), dim3(256), 0, stream>>>(Wq, Wkv, Wproj, w_bf);
  cls_kernel<<<dim3(96), dim3(256), 0, stream>>>(s_x, out);

  if (merged) {
    unsigned short* As    = (unsigned short*)(ws + WB);
    unsigned short* At    = (unsigned short*)(ws + WB + ABUF);
    unsigned short* q_bf  = (unsigned short*)(ws + WB + 2 * ABUF);
    unsigned short* kv_bf = (unsigned short*)(ws + WB + 3 * ABUF);
    aprep2_kernel<<<dim3(prep_blocks, 2), dim3(256), 0, stream>>>(
        s_x, t_x, clip_pos, vmae_pos, As, At, 0);
    gemm8<<<dim3(1764), dim3(512), 0, stream>>>(As, At, wq_bf, wkv_bf, q_bias, kv_bias,
                                                q_bf, kv_bf, 0);
    attn_kernel<<<dim3(9408), dim3(256), 0, stream>>>(q_bf, kv_bf, As);
    gemm_proj<<<dim3(1176), dim3(512), 0, stream>>>(As, wpj_bf, proj_bias, out);
  } else {
    unsigned short* buf1  = (unsigned short*)(ws + WB);
    unsigned short* q_bf  = (unsigned short*)(ws + WB + ABUF);
    unsigned short* kv_bf = (unsigned short*)(ws + WB + 2 * ABUF);
    aprep2_kernel<<<dim3(prep_blocks, 1), dim3(256), 0, stream>>>(
        s_x, t_x, clip_pos, vmae_pos, buf1, buf1, 0);          // y=0: s_x path
    gemm8<<<dim3(588), dim3(512), 0, stream>>>(buf1, buf1, wq_bf, wkv_bf, q_bias, kv_bias,
                                               q_bf, kv_bf, 0);
    aprep2_kernel<<<dim3(prep_blocks, 1), dim3(256), 0, stream>>>(
        s_x, t_x, clip_pos, vmae_pos, buf1, buf1, 1);          // ybase=1: t_x path
    gemm8<<<dim3(1176), dim3(512), 0, stream>>>(buf1, buf1, wq_bf, wkv_bf, q_bias, kv_bias,
                                                q_bf, kv_bf, 588);
    attn_kernel<<<dim3(9408), dim3(256), 0, stream>>>(q_bf, kv_bf, buf1);
    gemm_proj<<<dim3(1176), dim3(512), 0, stream>>>(buf1, wpj_bf, proj_bias, out);
  }
}